// Round 5
// baseline (135.937 us; speedup 1.0000x reference)
//
#include <hip/hip_runtime.h>
#include <math.h>

// Spectral NS projection step, 512x512 fp32 periodic — radix-8 register FFT.
//
// v5b: fused single kernel, 256 blocks x 128 thr (2 waves/block, 2 FFT
// lines per block per phase) so ALL 256 CUs are active every phase — v3/v4
// ran 128 blocks on 256 CUs (half the chip idle on latency-bound chains,
// device 48.6us at VALUBusy 3.6%). Software global barrier as v4.
// (v5 resubmit: round-4 container failure was infra — deadlock audit in
// journal; barrier is residency-safe at 4+ blocks/CU worst case.)
//
//  phase A : stencil + fwd row FFT of rows {2b,2b+1}; p kept in REGISTERS;
//            paired float4 transposed store of Zt.
//  phase B : column pair {b, 512-b} (block 0: {0,256}, self-mirror); fwd col
//            FFT, spectrum staged in LDS so conj(Z(-k)) is an intra-block
//            read (mirror wave = w^1), exact-1000-step-Jacobi multiplier,
//            inv col FFT, float2 transposed stores of W1.
//  phase C : inv row FFT of rows {2b,2b+1} + out = p(reg) - grad(phi).
//
// Multiplier (exact identity): M = r^1000 - (1-r^1000)/(4-s), r=s/4,
//   s=2cos ai+2cos aj;  4-s = 4(sin^2(ai/2)+sin^2(aj/2)) (cancellation-free)
//   W(k) = (beta/2)[(sx^2+sy^2) Z(k) + (sx+i sy)^2 conj(Z(-k))], beta=-10M/512^2
// sin/cos over k stepped by pi/8 Givens rotation (1 sincosf per thread).
//
// Stockham radix-8, 3 stages, reads always buf[t+64m] (conflict-free);
// scatter writes padded by idx+(idx>>3) -> near-uniform bank usage.

#define HH 512
#define WW 512
#define NCELL (HH * WW)
#define NU_C 0.1f
#define PI_F 3.14159265358979323846f
#define PADDED 576   // pad(511)=574
#define NBLK 256

__device__ __forceinline__ int padi(int i) { return i + (i >> 3); }

__device__ __forceinline__ float2 cadd(float2 a, float2 b) { return make_float2(a.x + b.x, a.y + b.y); }
__device__ __forceinline__ float2 csub(float2 a, float2 b) { return make_float2(a.x - b.x, a.y - b.y); }
__device__ __forceinline__ float2 cmul(float2 a, float2 b) {
    return make_float2(a.x * b.x - a.y * b.y, a.x * b.y + a.y * b.x);
}

// device-scope software barrier: one arrival counter per sync point (zeroed
// by memsetAsync before launch). Thread 0 releases prior writes, arrives,
// spins with short s_sleep; acquire load gives cross-XCD visibility.
__device__ __forceinline__ void gbar(unsigned* cnt) {
    __syncthreads();
    if (threadIdx.x == 0) {
        __threadfence();   // release all prior global writes device-wide
        __hip_atomic_fetch_add(cnt, 1u, __ATOMIC_ACQ_REL, __HIP_MEMORY_SCOPE_AGENT);
        while (__hip_atomic_load(cnt, __ATOMIC_ACQUIRE, __HIP_MEMORY_SCOPE_AGENT) < NBLK) {
            __builtin_amdgcn_s_sleep(2);
        }
    }
    __syncthreads();
}

// twiddle tables are stored FORWARD (cis(-theta)); inverse conjugates on use
template <int S>
__device__ __forceinline__ float2 cmul_tw(float2 a, float2 w) {
    float wy = (S < 0) ? w.y : -w.y;
    return make_float2(a.x * w.x - a.y * wy, a.x * wy + a.y * w.x);
}

// 8-point DFT, S=-1 forward (e^{-2pi i km/8}), S=+1 inverse
template <int S>
__device__ __forceinline__ void bfly8(float2 r[8]) {
    const float c = 0.70710678118654752f;
    const float s = (float)S;
    float2 e0 = cadd(r[0], r[4]), f0 = csub(r[0], r[4]);
    float2 e1 = cadd(r[2], r[6]), f1 = csub(r[2], r[6]);
    float2 g0 = cadd(r[1], r[5]), h0 = csub(r[1], r[5]);
    float2 g1 = cadd(r[3], r[7]), h1 = csub(r[3], r[7]);
    float2 E0 = cadd(e0, e1), E2 = csub(e0, e1);
    float2 if1 = make_float2(-s * f1.y, s * f1.x);       // s*i*f1
    float2 E1 = cadd(f0, if1), E3 = csub(f0, if1);
    float2 O0 = cadd(g0, g1), O2 = csub(g0, g1);
    float2 ih1 = make_float2(-s * h1.y, s * h1.x);
    float2 O1 = cadd(h0, ih1), O3 = csub(h0, ih1);
    float2 t1 = make_float2(c * (O1.x - s * O1.y), c * (O1.y + s * O1.x)); // W8^s1 * O1
    float2 t2 = make_float2(-s * O2.y, s * O2.x);                          // s*i*O2
    float2 t3 = make_float2(-c * (O3.x + s * O3.y), -c * (O3.y - s * O3.x));
    r[0] = cadd(E0, O0); r[4] = csub(E0, O0);
    r[1] = cadd(E1, t1); r[5] = csub(E1, t1);
    r[2] = cadd(E2, t2); r[6] = csub(E2, t2);
    r[3] = cadd(E3, t3); r[7] = csub(E3, t3);
}

struct Twid { float2 s1[8]; float2 s2[8]; };

__device__ __forceinline__ void make_tw(Twid& tw, int t) {
    float sn, cs;
    sincosf(-2.0f * PI_F * (float)(t & 7) * (1.0f / 64.0f), &sn, &cs);
    float2 T1 = make_float2(cs, sn);
    tw.s1[0] = make_float2(1.0f, 0.0f);
#pragma unroll
    for (int m = 1; m < 8; ++m) tw.s1[m] = cmul(tw.s1[m - 1], T1);
    sincosf(-2.0f * PI_F * (float)t * (1.0f / 512.0f), &sn, &cs);
    float2 T2 = make_float2(cs, sn);
    tw.s2[0] = make_float2(1.0f, 0.0f);
#pragma unroll
    for (int m = 1; m < 8; ++m) tw.s2[m] = cmul(tw.s2[m - 1], T2);
}

// 512-pt Stockham radix-8, one wave. In: r[m] = x[t+64m]. Out: r[k] = X[t+64k].
template <int S>
__device__ __forceinline__ void fft512(float2 r[8], const Twid& tw,
                                       float2* b0, float2* b1, int t) {
    bfly8<S>(r);
#pragma unroll
    for (int k = 0; k < 8; ++k) b0[padi(8 * t + k)] = r[k];
    __syncthreads();
#pragma unroll
    for (int m = 0; m < 8; ++m) r[m] = b0[padi(t + 64 * m)];
#pragma unroll
    for (int m = 1; m < 8; ++m) r[m] = cmul_tw<S>(r[m], tw.s1[m]);
    bfly8<S>(r);
    int base = ((t >> 3) << 6) + (t & 7);
#pragma unroll
    for (int k = 0; k < 8; ++k) b1[padi(base + 8 * k)] = r[k];
    __syncthreads();
#pragma unroll
    for (int m = 0; m < 8; ++m) r[m] = b1[padi(t + 64 * m)];
#pragma unroll
    for (int m = 1; m < 8; ++m) r[m] = cmul_tw<S>(r[m], tw.s2[m]);
    bfly8<S>(r);
}

// ---------------------------------------------------------------------------
__global__ __launch_bounds__(128) void fused(const float* __restrict__ X,
                                             const float* __restrict__ F,
                                             float2* __restrict__ Zt,
                                             float2* __restrict__ W1,
                                             unsigned* __restrict__ bar,
                                             float* __restrict__ out) {
    __shared__ float2 b0[2][PADDED], b1[2][PADDED];
    const int b = blockIdx.x;
    const int w = threadIdx.x >> 6;    // wave id 0..1
    const int t = threadIdx.x & 63;    // lane
    Twid tw; make_tw(tw, t);           // once for all three phases

    // ---------------- phase A: stencil + fwd row FFT (row i = 2b+w)
    const int i = 2 * b + w;
    const int ip = (i + 1) & 511, im = (i + 511) & 511;
    const float* X0 = X;
    const float* X1 = X + NCELL;
    float p0r[8], p1r[8];              // partial kept in registers for phase C
    float2 r[8];
#pragma unroll
    for (int m = 0; m < 8; ++m) {
        int j = t + 64 * m;
        int jp = (j + 1) & 511, jm = (j + 511) & 511;
        float x0c = X0[i * WW + j], x1c = X1[i * WW + j];
        float aip = X0[ip * WW + j], aim = X0[im * WW + j];
        float ajp = X0[i * WW + jp], ajm = X0[i * WW + jm];
        float p0 = -(x0c * (aip - aim) * 0.5f + x1c * (ajp - ajm) * 0.5f)
                 + NU_C * (aip + aim + ajp + ajm - 4.0f * x0c) + F[i * WW + j];
        float bip = X1[ip * WW + j], bim = X1[im * WW + j];
        float bjp = X1[i * WW + jp], bjm = X1[i * WW + jm];
        float p1 = -(x0c * (bip - bim) * 0.5f + x1c * (bjp - bjm) * 0.5f)
                 + NU_C * (bip + bim + bjp + bjm - 4.0f * x1c) + F[NCELL + i * WW + j];
        p0r[m] = p0; p1r[m] = p1;
        r[m] = make_float2(p0, p1);
    }
    fft512<-1>(r, tw, b0[w], b1[w], t);
    // stage spectra of the 2 rows (alias b0; per-wave region, no race)
#pragma unroll
    for (int k = 0; k < 8; ++k) b0[w][t + 64 * k] = r[k];
    __syncthreads();
#pragma unroll
    for (int q = 0; q < 4; ++q) {
        int f = threadIdx.x + 128 * q;
        float2 v0 = b0[0][f], v1 = b0[1][f];
        *reinterpret_cast<float4*>(&Zt[f * 512 + 2 * b]) = make_float4(v0.x, v0.y, v1.x, v1.y);
    }
    gbar(bar + 0);

    // ---------------- phase B: mirror-pair col FFT + multiplier + inverse
    // block b owns cols {b, 512-b} (block 0: {0,256}, both self-mirror);
    // mirror column of wave w lives in wave mw of the same block.
    const int cw = (b == 0) ? (w ? 256 : 0) : (w ? 512 - b : b);
    const int mw = (b == 0) ? w : (w ^ 1);
#pragma unroll
    for (int m = 0; m < 8; ++m) r[m] = Zt[cw * 512 + t + 64 * m];
    fft512<-1>(r, tw, b0[w], b1[w], t);
    // stage spectrum for mirror access (aliases b0; own-wave region)
#pragma unroll
    for (int k = 0; k < 8; ++k) b0[w][t + 64 * k] = r[k];
    __syncthreads();

    float shy, chy;
    sincosf(PI_F * (float)cw * (1.0f / 512.0f), &shy, &chy);
    float sy = 2.0f * shy * chy;   // sin(2 pi cw/512)
    float qy = shy * shy;          // sin^2(pi cw/512)
    // sin/cos(pi*ki/512) stepped by pi/8 per k (exact-constant Givens rotation)
    float sh, ch;
    sincosf(PI_F * (float)t * (1.0f / 512.0f), &sh, &ch);
    const float c8 = 0.92387953251128675613f;  // cos(pi/8)
    const float s8 = 0.38268343236508977173f;  // sin(pi/8)
#pragma unroll
    for (int k = 0; k < 8; ++k) {
        int ki = t + 64 * k;
        int mi = (HH - ki) & 511;
        float2 z  = r[k];                      // Z(k) (own spectrum, regs)
        float2 zc = b0[mw][mi];                // Z(-k) from mirror wave's LDS
        float sx = 2.0f * sh * ch;
        float qx = sh * sh;
        float qs = qx + qy;        // (4-s)/4 in [0,2]; 0 only at k=0
        float beta = 0.0f;
        if (ki != 0 || cw != 0) {
            float rN;              // r^1000 = |r|^1000, r = 1-qs
            if (qs < 1.0f)      rN = expf(1000.0f * log1pf(-qs));
            else if (qs > 1.0f) rN = expf(1000.0f * logf(qs - 1.0f));
            else                rN = 0.0f;
            float M = rN - (1.0f - rN) / (4.0f * qs);
            beta = -10.0f * M * (1.0f / (512.0f * 512.0f));
        }
        float su  = sx * sx + sy * sy;
        float u2x = sx * sx - sy * sy;
        float u2y = 2.0f * sx * sy;
        float cx = zc.x, cy = -zc.y;           // conj(Z(-k))
        float tx = u2x * cx - u2y * cy;
        float ty = u2x * cy + u2y * cx;
        float bh = 0.5f * beta;
        r[k] = make_float2(bh * (su * z.x + tx), bh * (su * z.y + ty));
        float nch = ch * c8 - sh * s8;         // advance angle by pi/8
        sh = sh * c8 + ch * s8;
        ch = nch;
    }
    __syncthreads();   // all mirror reads done before inverse FFT clobbers b0
    fft512<1>(r, tw, b0[w], b1[w], t);
    // stage results, then transposed float2 stores (cols not adjacent)
#pragma unroll
    for (int k = 0; k < 8; ++k) b0[w][t + 64 * k] = r[k];
    __syncthreads();
    {
        const int c0 = (b == 0) ? 0 : b;
        const int c1 = (b == 0) ? 256 : 512 - b;
#pragma unroll
        for (int q = 0; q < 4; ++q) {
            int f = threadIdx.x + 128 * q;
            W1[f * 512 + c0] = b0[0][f];
            W1[f * 512 + c1] = b0[1][f];
        }
    }
    gbar(bar + 16);

    // ---------------- phase C: inv row FFT (same rows) + output from reg-p
#pragma unroll
    for (int m = 0; m < 8; ++m) r[m] = W1[i * 512 + t + 64 * m];
    fft512<1>(r, tw, b0[w], b1[w], t);
#pragma unroll
    for (int k = 0; k < 8; ++k) {
        int j = t + 64 * k;
        out[i * WW + j]         = p0r[k] - r[k].x;
        out[NCELL + i * WW + j] = p1r[k] - r[k].y;
    }
}

// ---------------------------------------------------------------------------
extern "C" void kernel_launch(void* const* d_in, const int* in_sizes, int n_in,
                              void* d_out, int out_size, void* d_ws, size_t ws_size,
                              hipStream_t stream) {
    const float* X = (const float*)d_in[1];
    const float* F = (const float*)d_in[2];
    float* out = (float*)d_out;
    float* ws  = (float*)d_ws;

    float2* Zt = (float2*)ws;                 // NCELL float2 (2 MB)
    float2* W1 = Zt + NCELL;                  // NCELL float2 (2 MB)
    unsigned* bar = (unsigned*)(W1 + NCELL);  // 2 counters (zeroed per iter)

    hipMemsetAsync(bar, 0, 128, stream);
    fused<<<dim3(NBLK), dim3(128), 0, stream>>>(X, F, Zt, W1, bar, out);
}

// Round 6
// 78.786 us; speedup vs baseline: 1.7254x; 1.7254x over previous
//
#include <hip/hip_runtime.h>
#include <math.h>

// Spectral NS projection step, 512x512 fp32 periodic — radix-8 register FFT.
//
// v6: 3 plain kernels, ALL stores coalesced, transposes moved to LOAD side
// (stride-4KB gathers served by L2/MALL). Rationale: v4/v5 showed software
// grid barriers + partial-line scatter stores drain slower than HW kernel
// boundaries (v5: WRITE_SIZE 9.5->14.3MB amplification, device 88.6us);
// v2's plain kernels totaled ~30us device. This keeps v2's structure but
// removes the 4th kernel (S round-trip) and every scatter store.
//
//  kA (512x64) : stencil + fwd row FFT rows; store p + Zt ROW-major coalesced.
//  kB (256x128): mirror-pair cols {b,512-b} (block0:{0,256} self-mirror);
//                gather col from Zt, fwd FFT, spectrum in LDS so conj(Z(-k))
//                is an intra-block read (mirror wave = w^1), exact-Jacobi
//                multiplier, inv FFT, store W1 COLUMN-major coalesced.
//  kC (512x64) : gather row from W1 (col-major), inv row FFT,
//                out = p - grad(phi); p loads issued early to hide under FFT.
//
// Multiplier (exact identity): M = r^1000 - (1-r^1000)/(4-s), r=s/4,
//   s=2cos ai+2cos aj;  4-s = 4(sin^2(ai/2)+sin^2(aj/2)) (cancellation-free)
//   W(k) = (beta/2)[(sx^2+sy^2) Z(k) + (sx+i sy)^2 conj(Z(-k))], beta=-10M/512^2
// sin/cos over k stepped by pi/8 Givens rotation (1 sincosf per thread).
//
// Stockham radix-8, 3 stages, reads always buf[t+64m] (conflict-free);
// scatter writes padded by idx+(idx>>3) -> near-uniform bank usage.

#define HH 512
#define WW 512
#define NCELL (HH * WW)
#define NU_C 0.1f
#define PI_F 3.14159265358979323846f
#define PADDED 576   // pad(511)=574

__device__ __forceinline__ int padi(int i) { return i + (i >> 3); }

__device__ __forceinline__ float2 cadd(float2 a, float2 b) { return make_float2(a.x + b.x, a.y + b.y); }
__device__ __forceinline__ float2 csub(float2 a, float2 b) { return make_float2(a.x - b.x, a.y - b.y); }
__device__ __forceinline__ float2 cmul(float2 a, float2 b) {
    return make_float2(a.x * b.x - a.y * b.y, a.x * b.y + a.y * b.x);
}

// twiddle tables are stored FORWARD (cis(-theta)); inverse conjugates on use
template <int S>
__device__ __forceinline__ float2 cmul_tw(float2 a, float2 w) {
    float wy = (S < 0) ? w.y : -w.y;
    return make_float2(a.x * w.x - a.y * wy, a.x * wy + a.y * w.x);
}

// 8-point DFT, S=-1 forward (e^{-2pi i km/8}), S=+1 inverse
template <int S>
__device__ __forceinline__ void bfly8(float2 r[8]) {
    const float c = 0.70710678118654752f;
    const float s = (float)S;
    float2 e0 = cadd(r[0], r[4]), f0 = csub(r[0], r[4]);
    float2 e1 = cadd(r[2], r[6]), f1 = csub(r[2], r[6]);
    float2 g0 = cadd(r[1], r[5]), h0 = csub(r[1], r[5]);
    float2 g1 = cadd(r[3], r[7]), h1 = csub(r[3], r[7]);
    float2 E0 = cadd(e0, e1), E2 = csub(e0, e1);
    float2 if1 = make_float2(-s * f1.y, s * f1.x);       // s*i*f1
    float2 E1 = cadd(f0, if1), E3 = csub(f0, if1);
    float2 O0 = cadd(g0, g1), O2 = csub(g0, g1);
    float2 ih1 = make_float2(-s * h1.y, s * h1.x);
    float2 O1 = cadd(h0, ih1), O3 = csub(h0, ih1);
    float2 t1 = make_float2(c * (O1.x - s * O1.y), c * (O1.y + s * O1.x)); // W8^s1 * O1
    float2 t2 = make_float2(-s * O2.y, s * O2.x);                          // s*i*O2
    float2 t3 = make_float2(-c * (O3.x + s * O3.y), -c * (O3.y - s * O3.x));
    r[0] = cadd(E0, O0); r[4] = csub(E0, O0);
    r[1] = cadd(E1, t1); r[5] = csub(E1, t1);
    r[2] = cadd(E2, t2); r[6] = csub(E2, t2);
    r[3] = cadd(E3, t3); r[7] = csub(E3, t3);
}

struct Twid { float2 s1[8]; float2 s2[8]; };

__device__ __forceinline__ void make_tw(Twid& tw, int t) {
    float sn, cs;
    sincosf(-2.0f * PI_F * (float)(t & 7) * (1.0f / 64.0f), &sn, &cs);
    float2 T1 = make_float2(cs, sn);
    tw.s1[0] = make_float2(1.0f, 0.0f);
#pragma unroll
    for (int m = 1; m < 8; ++m) tw.s1[m] = cmul(tw.s1[m - 1], T1);
    sincosf(-2.0f * PI_F * (float)t * (1.0f / 512.0f), &sn, &cs);
    float2 T2 = make_float2(cs, sn);
    tw.s2[0] = make_float2(1.0f, 0.0f);
#pragma unroll
    for (int m = 1; m < 8; ++m) tw.s2[m] = cmul(tw.s2[m - 1], T2);
}

// 512-pt Stockham radix-8, one wave. In: r[m] = x[t+64m]. Out: r[k] = X[t+64k].
template <int S>
__device__ __forceinline__ void fft512(float2 r[8], const Twid& tw,
                                       float2* b0, float2* b1, int t) {
    bfly8<S>(r);
#pragma unroll
    for (int k = 0; k < 8; ++k) b0[padi(8 * t + k)] = r[k];
    __syncthreads();
#pragma unroll
    for (int m = 0; m < 8; ++m) r[m] = b0[padi(t + 64 * m)];
#pragma unroll
    for (int m = 1; m < 8; ++m) r[m] = cmul_tw<S>(r[m], tw.s1[m]);
    bfly8<S>(r);
    int base = ((t >> 3) << 6) + (t & 7);
#pragma unroll
    for (int k = 0; k < 8; ++k) b1[padi(base + 8 * k)] = r[k];
    __syncthreads();
#pragma unroll
    for (int m = 0; m < 8; ++m) r[m] = b1[padi(t + 64 * m)];
#pragma unroll
    for (int m = 1; m < 8; ++m) r[m] = cmul_tw<S>(r[m], tw.s2[m]);
    bfly8<S>(r);
}

// --------------------------------------------- phase A: stencil + row FFT
__global__ __launch_bounds__(64) void kA(const float* __restrict__ X,
                                         const float* __restrict__ F,
                                         float* __restrict__ p,
                                         float2* __restrict__ Zt) {
    __shared__ float2 b0[PADDED], b1[PADDED];
    int i = blockIdx.x, t = threadIdx.x;
    Twid tw; make_tw(tw, t);
    int ip = (i + 1) & 511, im = (i + 511) & 511;
    const float* X0 = X;
    const float* X1 = X + NCELL;
    float2 r[8];
#pragma unroll
    for (int m = 0; m < 8; ++m) {
        int j = t + 64 * m;
        int jp = (j + 1) & 511, jm = (j + 511) & 511;
        float x0c = X0[i * WW + j], x1c = X1[i * WW + j];
        float aip = X0[ip * WW + j], aim = X0[im * WW + j];
        float ajp = X0[i * WW + jp], ajm = X0[i * WW + jm];
        float p0 = -(x0c * (aip - aim) * 0.5f + x1c * (ajp - ajm) * 0.5f)
                 + NU_C * (aip + aim + ajp + ajm - 4.0f * x0c) + F[i * WW + j];
        float bip = X1[ip * WW + j], bim = X1[im * WW + j];
        float bjp = X1[i * WW + jp], bjm = X1[i * WW + jm];
        float p1 = -(x0c * (bip - bim) * 0.5f + x1c * (bjp - bjm) * 0.5f)
                 + NU_C * (bip + bim + bjp + bjm - 4.0f * x1c) + F[NCELL + i * WW + j];
        p[i * WW + j] = p0;
        p[NCELL + i * WW + j] = p1;
        r[m] = make_float2(p0, p1);
    }
    fft512<-1>(r, tw, b0, b1, t);
    // ROW-major coalesced spectrum store (transpose deferred to kB's gather)
#pragma unroll
    for (int k = 0; k < 8; ++k) Zt[i * 512 + t + 64 * k] = r[k];
}

// ------- phase B: mirror-pair col FFT + multiplier + inverse col FFT
// block b owns cols {b, 512-b} (block 0: {0,256}, both self-mirror).
__global__ __launch_bounds__(128) void kB(const float2* __restrict__ Zt,
                                          float2* __restrict__ W1) {
    __shared__ float2 b0[2][PADDED], b1[2][PADDED];
    const int b = blockIdx.x;
    const int w = threadIdx.x >> 6, t = threadIdx.x & 63;
    const int cw = (b == 0) ? (w ? 256 : 0) : (w ? 512 - b : b);
    const int mw = (b == 0) ? w : (w ^ 1);
    Twid tw; make_tw(tw, t);
    float2 r[8];
    // gather column cw from row-major Zt (stride-4KB, L2/MALL-served)
#pragma unroll
    for (int m = 0; m < 8; ++m) r[m] = Zt[(t + 64 * m) * 512 + cw];
    fft512<-1>(r, tw, b0[w], b1[w], t);
    // stage spectrum for mirror access (aliases b0; own-wave region)
#pragma unroll
    for (int k = 0; k < 8; ++k) b0[w][t + 64 * k] = r[k];
    __syncthreads();

    float shy, chy;
    sincosf(PI_F * (float)cw * (1.0f / 512.0f), &shy, &chy);
    float sy = 2.0f * shy * chy;   // sin(2 pi cw/512)
    float qy = shy * shy;          // sin^2(pi cw/512)
    // sin/cos(pi*ki/512) stepped by pi/8 per k (exact-constant Givens rotation)
    float sh, ch;
    sincosf(PI_F * (float)t * (1.0f / 512.0f), &sh, &ch);
    const float c8 = 0.92387953251128675613f;  // cos(pi/8)
    const float s8 = 0.38268343236508977173f;  // sin(pi/8)
#pragma unroll
    for (int k = 0; k < 8; ++k) {
        int ki = t + 64 * k;
        int mi = (HH - ki) & 511;
        float2 z  = r[k];                      // Z(k) (own spectrum, regs)
        float2 zc = b0[mw][mi];                // Z(-k) from mirror wave's LDS
        float sx = 2.0f * sh * ch;
        float qx = sh * sh;
        float qs = qx + qy;        // (4-s)/4 in [0,2]; 0 only at k=0
        float beta = 0.0f;
        if (ki != 0 || cw != 0) {
            float rN;              // r^1000 = |r|^1000, r = 1-qs
            if (qs < 1.0f)      rN = expf(1000.0f * log1pf(-qs));
            else if (qs > 1.0f) rN = expf(1000.0f * logf(qs - 1.0f));
            else                rN = 0.0f;
            float M = rN - (1.0f - rN) / (4.0f * qs);
            beta = -10.0f * M * (1.0f / (512.0f * 512.0f));
        }
        float su  = sx * sx + sy * sy;
        float u2x = sx * sx - sy * sy;
        float u2y = 2.0f * sx * sy;
        float cx = zc.x, cy = -zc.y;           // conj(Z(-k))
        float tx = u2x * cx - u2y * cy;
        float ty = u2x * cy + u2y * cx;
        float bh = 0.5f * beta;
        r[k] = make_float2(bh * (su * z.x + tx), bh * (su * z.y + ty));
        float nch = ch * c8 - sh * s8;         // advance angle by pi/8
        sh = sh * c8 + ch * s8;
        ch = nch;
    }
    __syncthreads();   // all mirror reads done before inverse FFT clobbers b0
    fft512<1>(r, tw, b0[w], b1[w], t);
    // COLUMN-major coalesced store (transpose deferred to kC's gather)
#pragma unroll
    for (int k = 0; k < 8; ++k) W1[cw * 512 + t + 64 * k] = r[k];
}

// --------------------------------------- phase C: inverse row FFT + output
__global__ __launch_bounds__(64) void kC(const float2* __restrict__ W1,
                                         const float* __restrict__ p,
                                         float* __restrict__ out) {
    __shared__ float2 b0[PADDED], b1[PADDED];
    int i = blockIdx.x, t = threadIdx.x;
    Twid tw; make_tw(tw, t);
    // issue p loads early (coalesced) so they complete under the FFT
    float pp0[8], pp1[8];
#pragma unroll
    for (int k = 0; k < 8; ++k) {
        pp0[k] = p[i * WW + t + 64 * k];
        pp1[k] = p[NCELL + i * WW + t + 64 * k];
    }
    float2 r[8];
    // gather row i from col-major W1 (stride-4KB, L2/MALL-served)
#pragma unroll
    for (int m = 0; m < 8; ++m) r[m] = W1[(t + 64 * m) * 512 + i];
    fft512<1>(r, tw, b0, b1, t);
#pragma unroll
    for (int k = 0; k < 8; ++k) {
        int j = t + 64 * k;
        out[i * WW + j]         = pp0[k] - r[k].x;
        out[NCELL + i * WW + j] = pp1[k] - r[k].y;
    }
}

// ---------------------------------------------------------------------------
extern "C" void kernel_launch(void* const* d_in, const int* in_sizes, int n_in,
                              void* d_out, int out_size, void* d_ws, size_t ws_size,
                              hipStream_t stream) {
    const float* X = (const float*)d_in[1];
    const float* F = (const float*)d_in[2];
    float* out = (float*)d_out;
    float* ws  = (float*)d_ws;

    float*  p  = ws;                          // 2*NCELL floats (2 MB)
    float2* Zt = (float2*)(ws + 2 * NCELL);   // NCELL float2 (2 MB), row-major
    float2* W1 = Zt + NCELL;                  // NCELL float2 (2 MB), col-major

    kA<<<dim3(512), dim3(64),  0, stream>>>(X, F, p, Zt);
    kB<<<dim3(256), dim3(128), 0, stream>>>(Zt, W1);
    kC<<<dim3(512), dim3(64),  0, stream>>>(W1, p, out);
}

// Round 7
// 75.036 us; speedup vs baseline: 1.8116x; 1.0500x over previous
//
#include <hip/hip_runtime.h>
#include <math.h>

// Spectral NS projection step, 512x512 fp32 periodic — radix-8 register FFT.
//
// v7: v6's 3-kernel all-coalesced-store structure +
//  (1) XCD-contiguous work maps: blockIdx -> (line) chosen so each XCD owns
//      CONTIGUOUS column/row spans; the 16 lines sharing a 128B cacheline of
//      the transposed gather are then consumed within ONE XCD's private L2
//      (default round-robin spread them over 8 XCDs -> ~1/16 line reuse,
//      every gather at L3/HBM latency).
//  (2) p recomputed in kC from X,F (bitwise-identical stencil) — deletes the
//      4MB p round-trip; kC issues W1 gathers first so stencil VALU hides
//      under gather latency.
//
//  kA (512x64) : row i=(b&7)*64+(b>>3); stencil + fwd row FFT; Zt row-major.
//  kB (256x128): base col c0=(b&7)*32+(b>>3); wave w: col {c0, 512-c0}
//                (c0==0 -> {0,256}, self-mirror); gather col from Zt, fwd
//                FFT, conj(Z(-k)) via intra-block LDS (mirror wave), exact
//                1000-step-Jacobi multiplier, inv FFT, W1 col-major.
//  kC (512x64) : row i=(b&7)*64+(b>>3); gather row from W1, inv row FFT,
//                recompute p, out = p - grad(phi).
//
// Multiplier (exact identity): M = r^1000 - (1-r^1000)/(4-s), r=s/4,
//   s=2cos ai+2cos aj;  4-s = 4(sin^2(ai/2)+sin^2(aj/2)) (cancellation-free)
//   W(k) = (beta/2)[(sx^2+sy^2) Z(k) + (sx+i sy)^2 conj(Z(-k))], beta=-10M/512^2
// sin/cos over k stepped by pi/8 Givens rotation (1 sincosf per thread).
//
// Stockham radix-8, 3 stages, reads always buf[t+64m] (conflict-free);
// LDS scatter writes padded by idx+(idx>>3) -> near-uniform bank usage.

#define HH 512
#define WW 512
#define NCELL (HH * WW)
#define NU_C 0.1f
#define PI_F 3.14159265358979323846f
#define PADDED 576   // pad(511)=574

__device__ __forceinline__ int padi(int i) { return i + (i >> 3); }

__device__ __forceinline__ float2 cadd(float2 a, float2 b) { return make_float2(a.x + b.x, a.y + b.y); }
__device__ __forceinline__ float2 csub(float2 a, float2 b) { return make_float2(a.x - b.x, a.y - b.y); }
__device__ __forceinline__ float2 cmul(float2 a, float2 b) {
    return make_float2(a.x * b.x - a.y * b.y, a.x * b.y + a.y * b.x);
}

// twiddle tables are stored FORWARD (cis(-theta)); inverse conjugates on use
template <int S>
__device__ __forceinline__ float2 cmul_tw(float2 a, float2 w) {
    float wy = (S < 0) ? w.y : -w.y;
    return make_float2(a.x * w.x - a.y * wy, a.x * wy + a.y * w.x);
}

// 8-point DFT, S=-1 forward (e^{-2pi i km/8}), S=+1 inverse
template <int S>
__device__ __forceinline__ void bfly8(float2 r[8]) {
    const float c = 0.70710678118654752f;
    const float s = (float)S;
    float2 e0 = cadd(r[0], r[4]), f0 = csub(r[0], r[4]);
    float2 e1 = cadd(r[2], r[6]), f1 = csub(r[2], r[6]);
    float2 g0 = cadd(r[1], r[5]), h0 = csub(r[1], r[5]);
    float2 g1 = cadd(r[3], r[7]), h1 = csub(r[3], r[7]);
    float2 E0 = cadd(e0, e1), E2 = csub(e0, e1);
    float2 if1 = make_float2(-s * f1.y, s * f1.x);       // s*i*f1
    float2 E1 = cadd(f0, if1), E3 = csub(f0, if1);
    float2 O0 = cadd(g0, g1), O2 = csub(g0, g1);
    float2 ih1 = make_float2(-s * h1.y, s * h1.x);
    float2 O1 = cadd(h0, ih1), O3 = csub(h0, ih1);
    float2 t1 = make_float2(c * (O1.x - s * O1.y), c * (O1.y + s * O1.x)); // W8^s1 * O1
    float2 t2 = make_float2(-s * O2.y, s * O2.x);                          // s*i*O2
    float2 t3 = make_float2(-c * (O3.x + s * O3.y), -c * (O3.y - s * O3.x));
    r[0] = cadd(E0, O0); r[4] = csub(E0, O0);
    r[1] = cadd(E1, t1); r[5] = csub(E1, t1);
    r[2] = cadd(E2, t2); r[6] = csub(E2, t2);
    r[3] = cadd(E3, t3); r[7] = csub(E3, t3);
}

struct Twid { float2 s1[8]; float2 s2[8]; };

__device__ __forceinline__ void make_tw(Twid& tw, int t) {
    float sn, cs;
    sincosf(-2.0f * PI_F * (float)(t & 7) * (1.0f / 64.0f), &sn, &cs);
    float2 T1 = make_float2(cs, sn);
    tw.s1[0] = make_float2(1.0f, 0.0f);
#pragma unroll
    for (int m = 1; m < 8; ++m) tw.s1[m] = cmul(tw.s1[m - 1], T1);
    sincosf(-2.0f * PI_F * (float)t * (1.0f / 512.0f), &sn, &cs);
    float2 T2 = make_float2(cs, sn);
    tw.s2[0] = make_float2(1.0f, 0.0f);
#pragma unroll
    for (int m = 1; m < 8; ++m) tw.s2[m] = cmul(tw.s2[m - 1], T2);
}

// 512-pt Stockham radix-8, one wave. In: r[m] = x[t+64m]. Out: r[k] = X[t+64k].
template <int S>
__device__ __forceinline__ void fft512(float2 r[8], const Twid& tw,
                                       float2* b0, float2* b1, int t) {
    bfly8<S>(r);
#pragma unroll
    for (int k = 0; k < 8; ++k) b0[padi(8 * t + k)] = r[k];
    __syncthreads();
#pragma unroll
    for (int m = 0; m < 8; ++m) r[m] = b0[padi(t + 64 * m)];
#pragma unroll
    for (int m = 1; m < 8; ++m) r[m] = cmul_tw<S>(r[m], tw.s1[m]);
    bfly8<S>(r);
    int base = ((t >> 3) << 6) + (t & 7);
#pragma unroll
    for (int k = 0; k < 8; ++k) b1[padi(base + 8 * k)] = r[k];
    __syncthreads();
#pragma unroll
    for (int m = 0; m < 8; ++m) r[m] = b1[padi(t + 64 * m)];
#pragma unroll
    for (int m = 1; m < 8; ++m) r[m] = cmul_tw<S>(r[m], tw.s2[m]);
    bfly8<S>(r);
}

// stencil: partial for both fields at row i, cols t+64m (bitwise-shared by kA/kC)
__device__ __forceinline__ void stencil_row(const float* __restrict__ X,
                                            const float* __restrict__ F,
                                            int i, int t, float p0r[8], float p1r[8]) {
    const int ip = (i + 1) & 511, im = (i + 511) & 511;
    const float* X0 = X;
    const float* X1 = X + NCELL;
#pragma unroll
    for (int m = 0; m < 8; ++m) {
        int j = t + 64 * m;
        int jp = (j + 1) & 511, jm = (j + 511) & 511;
        float x0c = X0[i * WW + j], x1c = X1[i * WW + j];
        float aip = X0[ip * WW + j], aim = X0[im * WW + j];
        float ajp = X0[i * WW + jp], ajm = X0[i * WW + jm];
        p0r[m] = -(x0c * (aip - aim) * 0.5f + x1c * (ajp - ajm) * 0.5f)
               + NU_C * (aip + aim + ajp + ajm - 4.0f * x0c) + F[i * WW + j];
        float bip = X1[ip * WW + j], bim = X1[im * WW + j];
        float bjp = X1[i * WW + jp], bjm = X1[i * WW + jm];
        p1r[m] = -(x0c * (bip - bim) * 0.5f + x1c * (bjp - bjm) * 0.5f)
               + NU_C * (bip + bim + bjp + bjm - 4.0f * x1c) + F[NCELL + i * WW + j];
    }
}

// --------------------------------------------- phase A: stencil + row FFT
__global__ __launch_bounds__(64) void kA(const float* __restrict__ X,
                                         const float* __restrict__ F,
                                         float2* __restrict__ Zt) {
    __shared__ float2 b0[PADDED], b1[PADDED];
    const int b = blockIdx.x, t = threadIdx.x;
    const int i = (b & 7) * 64 + (b >> 3);    // XCD x owns rows [64x,64x+64)
    Twid tw; make_tw(tw, t);
    float p0r[8], p1r[8];
    stencil_row(X, F, i, t, p0r, p1r);
    float2 r[8];
#pragma unroll
    for (int m = 0; m < 8; ++m) r[m] = make_float2(p0r[m], p1r[m]);
    fft512<-1>(r, tw, b0, b1, t);
    // ROW-major coalesced spectrum store (transpose deferred to kB's gather)
#pragma unroll
    for (int k = 0; k < 8; ++k) Zt[i * 512 + t + 64 * k] = r[k];
}

// ------- phase B: mirror-pair col FFT + multiplier + inverse col FFT
// base col c0=(b&7)*32+(b>>3): XCD x owns cols [32x,32x+32) + mirror span.
__global__ __launch_bounds__(128) void kB(const float2* __restrict__ Zt,
                                          float2* __restrict__ W1) {
    __shared__ float2 b0[2][PADDED], b1[2][PADDED];
    const int b = blockIdx.x;
    const int w = threadIdx.x >> 6, t = threadIdx.x & 63;
    const int c0 = (b & 7) * 32 + (b >> 3);   // 0..255, all distinct
    const int cw = (c0 == 0) ? (w ? 256 : 0) : (w ? 512 - c0 : c0);
    const int mw = (c0 == 0) ? w : (w ^ 1);
    Twid tw; make_tw(tw, t);
    float2 r[8];
    // gather column cw from row-major Zt (16-col cacheline groups XCD-local)
#pragma unroll
    for (int m = 0; m < 8; ++m) r[m] = Zt[(t + 64 * m) * 512 + cw];
    fft512<-1>(r, tw, b0[w], b1[w], t);
    // stage spectrum for mirror access (aliases b0; own-wave region)
#pragma unroll
    for (int k = 0; k < 8; ++k) b0[w][t + 64 * k] = r[k];
    __syncthreads();

    float shy, chy;
    sincosf(PI_F * (float)cw * (1.0f / 512.0f), &shy, &chy);
    float sy = 2.0f * shy * chy;   // sin(2 pi cw/512)
    float qy = shy * shy;          // sin^2(pi cw/512)
    // sin/cos(pi*ki/512) stepped by pi/8 per k (exact-constant Givens rotation)
    float sh, ch;
    sincosf(PI_F * (float)t * (1.0f / 512.0f), &sh, &ch);
    const float c8 = 0.92387953251128675613f;  // cos(pi/8)
    const float s8 = 0.38268343236508977173f;  // sin(pi/8)
#pragma unroll
    for (int k = 0; k < 8; ++k) {
        int ki = t + 64 * k;
        int mi = (HH - ki) & 511;
        float2 z  = r[k];                      // Z(k) (own spectrum, regs)
        float2 zc = b0[mw][mi];                // Z(-k) from mirror wave's LDS
        float sx = 2.0f * sh * ch;
        float qx = sh * sh;
        float qs = qx + qy;        // (4-s)/4 in [0,2]; 0 only at k=0
        float beta = 0.0f;
        if (ki != 0 || cw != 0) {
            float rN;              // r^1000 = |r|^1000, r = 1-qs
            if (qs < 1.0f)      rN = expf(1000.0f * log1pf(-qs));
            else if (qs > 1.0f) rN = expf(1000.0f * logf(qs - 1.0f));
            else                rN = 0.0f;
            float M = rN - (1.0f - rN) / (4.0f * qs);
            beta = -10.0f * M * (1.0f / (512.0f * 512.0f));
        }
        float su  = sx * sx + sy * sy;
        float u2x = sx * sx - sy * sy;
        float u2y = 2.0f * sx * sy;
        float cx = zc.x, cy = -zc.y;           // conj(Z(-k))
        float tx = u2x * cx - u2y * cy;
        float ty = u2x * cy + u2y * cx;
        float bh = 0.5f * beta;
        r[k] = make_float2(bh * (su * z.x + tx), bh * (su * z.y + ty));
        float nch = ch * c8 - sh * s8;         // advance angle by pi/8
        sh = sh * c8 + ch * s8;
        ch = nch;
    }
    __syncthreads();   // all mirror reads done before inverse FFT clobbers b0
    fft512<1>(r, tw, b0[w], b1[w], t);
    // COLUMN-major coalesced store (transpose deferred to kC's gather)
#pragma unroll
    for (int k = 0; k < 8; ++k) W1[cw * 512 + t + 64 * k] = r[k];
}

// --------------------------------------- phase C: inverse row FFT + output
__global__ __launch_bounds__(64) void kC(const float2* __restrict__ W1,
                                         const float* __restrict__ X,
                                         const float* __restrict__ F,
                                         float* __restrict__ out) {
    __shared__ float2 b0[PADDED], b1[PADDED];
    const int b = blockIdx.x, t = threadIdx.x;
    const int i = (b & 7) * 64 + (b >> 3);    // XCD x owns rows [64x,64x+64)
    Twid tw; make_tw(tw, t);
    float2 r[8];
    // issue row-gather from col-major W1 first (16-row cacheline groups
    // XCD-local); stencil recompute below hides under the gather latency
#pragma unroll
    for (int m = 0; m < 8; ++m) r[m] = W1[(t + 64 * m) * 512 + i];
    float p0r[8], p1r[8];
    stencil_row(X, F, i, t, p0r, p1r);         // bitwise-identical to kA's p
    fft512<1>(r, tw, b0, b1, t);
#pragma unroll
    for (int k = 0; k < 8; ++k) {
        int j = t + 64 * k;
        out[i * WW + j]         = p0r[k] - r[k].x;
        out[NCELL + i * WW + j] = p1r[k] - r[k].y;
    }
}

// ---------------------------------------------------------------------------
extern "C" void kernel_launch(void* const* d_in, const int* in_sizes, int n_in,
                              void* d_out, int out_size, void* d_ws, size_t ws_size,
                              hipStream_t stream) {
    const float* X = (const float*)d_in[1];
    const float* F = (const float*)d_in[2];
    float* out = (float*)d_out;
    float* ws  = (float*)d_ws;

    float2* Zt = (float2*)ws;                 // NCELL float2 (2 MB), row-major
    float2* W1 = Zt + NCELL;                  // NCELL float2 (2 MB), col-major

    kA<<<dim3(512), dim3(64),  0, stream>>>(X, F, Zt);
    kB<<<dim3(256), dim3(128), 0, stream>>>(Zt, W1);
    kC<<<dim3(512), dim3(64),  0, stream>>>(W1, X, F, out);
}